// Round 1
// 79.984 us; speedup vs baseline: 1.0168x; 1.0168x over previous
//
#include <hip/hip_runtime.h>

// N-body all-pairs gravitational force, N=8192, fp32.
//
// Round-8: fix the occupancy miscount from r7. r7's "1024 blocks x 2 waves
// = 4 waves/SIMD" was wrong: 2048 waves / 1024 SIMDs = 2 waves/SIMD. At
// 2 waves/SIMD the ds_read->sub->fma3->rsq(trans)->mul3->fma chain stalls
// can't be hidden (issue floor ~14us, measured ~38us).
//  - BLOCK=256, IBLK=2 -> 512 i's/block, 16 i-tiles (unchanged IBODIES)
//  - JSPLIT=64 -> JPER=128 j's/block, 2KB LDS tile, ONE barrier (unchanged)
//  - grid 16x64 = 1024 blocks x 4 waves = 4096 waves = 4 waves/SIMD (2x TLP)
//  - partial traffic unchanged (6.3MB) -> clean A/B on the TLP variable
//  - per-pair math bit-identical to r7 (absmax should stay 0.125)
// Prediction: nbody ~38 -> ~20-24us, dur_us 81.3 -> ~64-68.

constexpr int   NBODY   = 8192;
constexpr int   BLOCK   = 256;
constexpr int   IBLK    = 2;
constexpr int   IBODIES = BLOCK * IBLK;        // 512 i's per block
constexpr int   JSPLIT  = 64;
constexpr int   JPER    = NBODY / JSPLIT;      // 128 j's per block
constexpr float SOFT2   = 0.01f * 0.01f;
constexpr int   OUTE    = NBODY * 3;           // 24576

__global__ __launch_bounds__(BLOCK, 4) void nbody_forces(
    const float* __restrict__ pos,       // [N,3]
    const float* __restrict__ mass,      // [N]
    float*       __restrict__ part)      // [JSPLIT][N*3] partials
{
    const int tid   = threadIdx.x;
    const int iBase = blockIdx.x * IBODIES + tid;
    const int j0    = blockIdx.y * JPER;

    __shared__ float4 sh[JPER];
    if (tid < JPER) {                    // JPER=128 < BLOCK=256: half stage
        const int j = j0 + tid;
        sh[tid] = make_float4(pos[3 * j + 0], pos[3 * j + 1], pos[3 * j + 2], mass[j]);
    }

    float px[IBLK], py[IBLK], pz[IBLK];
    #pragma unroll
    for (int b = 0; b < IBLK; ++b) {
        const int i = iBase + b * BLOCK;
        px[b] = pos[3 * i + 0];
        py[b] = pos[3 * i + 1];
        pz[b] = pos[3 * i + 2];
    }
    __syncthreads();

    float fx[IBLK], fy[IBLK], fz[IBLK];
    #pragma unroll
    for (int b = 0; b < IBLK; ++b) { fx[b] = 0.f; fy[b] = 0.f; fz[b] = 0.f; }

    #pragma unroll 8
    for (int k = 0; k < JPER; ++k) {
        const float4 p = sh[k];            // uniform addr -> HW broadcast
        #pragma unroll
        for (int b = 0; b < IBLK; ++b) {   // 2 independent chains x 4 waves/SIMD
            const float dx = p.x - px[b];
            const float dy = p.y - py[b];
            const float dz = p.z - pz[b];
            const float d2 = fmaf(dx, dx, fmaf(dy, dy, fmaf(dz, dz, SOFT2)));
            const float inv = __builtin_amdgcn_rsqf(d2);    // v_rsq_f32
            const float s   = p.w * inv * inv * inv;        // G = 1
            fx[b] = fmaf(s, dx, fx[b]);
            fy[b] = fmaf(s, dy, fy[b]);
            fz[b] = fmaf(s, dz, fz[b]);
            // j == i: diff = 0 -> contribution 0, matches reference.
        }
    }

    float* dst = part + (size_t)blockIdx.y * OUTE;
    #pragma unroll
    for (int b = 0; b < IBLK; ++b) {
        const int i = iBase + b * BLOCK;
        dst[3 * i + 0] = fx[b];
        dst[3 * i + 1] = fy[b];
        dst[3 * i + 2] = fz[b];
    }
}

__global__ __launch_bounds__(256) void reduce_kernel(
    const float* __restrict__ part,      // [JSPLIT][OUTE]
    float*       __restrict__ out)       // [OUTE]
{
    const int e = blockIdx.x * blockDim.x + threadIdx.x;   // 0..OUTE-1
    float s = 0.f;
    #pragma unroll 8
    for (int k = 0; k < JSPLIT; ++k)
        s += part[(size_t)k * OUTE + e];
    out[e] = s;
}

extern "C" void kernel_launch(void* const* d_in, const int* in_sizes, int n_in,
                              void* d_out, int out_size, void* d_ws, size_t ws_size,
                              hipStream_t stream) {
    const float* pos  = (const float*)d_in[0];
    const float* mass = (const float*)d_in[1];
    float* out = (float*)d_out;

    float* part = (float*)d_ws;          // [JSPLIT][OUTE] = 6.3 MB

    dim3 grid(NBODY / IBODIES, JSPLIT);  // (16, 64) = 1024 blocks
    nbody_forces<<<grid, BLOCK, 0, stream>>>(pos, mass, part);

    reduce_kernel<<<OUTE / 256, 256, 0, stream>>>(part, out);
}